// Round 10
// baseline (1160.099 us; speedup 1.0000x reference)
//
#include <hip/hip_runtime.h>
#include <hip/hip_cooperative_groups.h>
#include <hip/hip_bf16.h>
#include <hip/hip_fp16.h>

namespace cg = cooperative_groups;

#define DD 64
#define EPSV 1e-5f
#define NSLICE 16
#define CGBLOCKS 1024

typedef __attribute__((ext_vector_type(8))) _Float16 f16x8;
typedef __attribute__((ext_vector_type(4))) float f32x4;

static __device__ __forceinline__ float fatomic_add(float* p, float v) {
#if defined(__HIP_DEVICE_COMPILE__)
    return unsafeAtomicAdd(p, v);
#else
    return 0.f;
#endif
}

static __device__ __forceinline__ float gelu_exact(float x) {
    return 0.5f * x * (1.0f + erff(x * 0.70710678118654752f));
}

// accumulate 8 halfs (uint4) into 8 fp32 accumulators
static __device__ __forceinline__ void acc_u4(float* a8, uint4 v) {
    const __half2* hp = reinterpret_cast<const __half2*>(&v);
#pragma unroll
    for (int p = 0; p < 4; ++p) {
        float2 f = __half22float2(hp[p]);
        a8[2 * p] += f.x;
        a8[2 * p + 1] += f.y;
    }
}

#define ACHUNK 2048
#define NBMAX 400

// ---------------- bucket-level edge count ----------------
__global__ __launch_bounds__(1024) void k_bcount(const int* __restrict__ dst,
                                                 int* __restrict__ bucketCnt,
                                                 int e, int nbuck) {
    __shared__ int h[NBMAX];
    int t = threadIdx.x;
    for (int i = t; i < nbuck; i += 1024) h[i] = 0;
    __syncthreads();
    int base = blockIdx.x * 8192;
#pragma unroll
    for (int k = 0; k < 8; ++k) {
        int i = base + k * 1024 + t;
        if (i < e) atomicAdd(&h[dst[i] >> 8], 1);
    }
    __syncthreads();
    for (int i = t; i < nbuck; i += 1024)
        if (h[i]) atomicAdd(&bucketCnt[i], h[i]);
}

// scan bucket counts -> bbase (exclusive), seed binA cursors, write offs[n]
__global__ __launch_bounds__(512) void k_bscan2(const int* __restrict__ bucketCnt,
                                                int* __restrict__ bbase,
                                                int* __restrict__ bcur,
                                                int* __restrict__ offs,
                                                int nbuck, int etotal, int n) {
    __shared__ int ws[8];
    int t = threadIdx.x, lane = t & 63, wv = t >> 6;
    int v = (t < nbuck) ? bucketCnt[t] : 0;
    int x = v;
#pragma unroll
    for (int o = 1; o < 64; o <<= 1) {
        int u = __shfl_up(x, o, 64);
        if (lane >= o) x += u;
    }
    if (lane == 63) ws[wv] = x;
    __syncthreads();
    int add = 0;
    for (int w = 0; w < wv; ++w) add += ws[w];
    int excl = add + x - v;
    if (t < nbuck) {
        bbase[t] = excl;
        bcur[t] = excl;
    }
    if (t == 0) {
        bbase[nbuck] = etotal;
        offs[n] = etotal;
    }
}

// ---------------- degree hist + bnd + zero rows + sinfo tail ----------------
__global__ __launch_bounds__(1024) void k_dhist(const int* __restrict__ off,
                                                int* __restrict__ dcount,
                                                const int* __restrict__ batch,
                                                int* __restrict__ bnd,
                                                __half* __restrict__ mA,
                                                __half* __restrict__ mB,
                                                int4* __restrict__ sinfo,
                                                int n, int g, int ntiles) {
    __shared__ int h[256];
    int t = threadIdx.x;
    if (t < 256) h[t] = 0;
    __syncthreads();
    int i = blockIdx.x * 1024 + t;
    if (i < n) {
        int d = min(off[i + 1] - off[i], 255);
        atomicAdd(&h[d], 1);
        int b = batch[i];
        if (i == 0)
            for (int q = 0; q <= b; ++q) bnd[q] = 0;
        else {
            int pb = batch[i - 1];
            for (int q = pb + 1; q <= b; ++q) bnd[q] = i;
        }
        if (i == n - 1)
            for (int q = b + 1; q <= g; ++q) bnd[q] = n;
    }
    if (blockIdx.x == 0 && t < 64) {  // dummy zero row at index n (gather tail identity)
        mA[(size_t)n * 64 + t] = __float2half_rn(0.f);
        mB[(size_t)n * 64 + t] = __float2half_rn(0.f);
    }
    int pad = ntiles * 16 - n;
    if (blockIdx.x == 0 && t < pad) sinfo[n + t] = make_int4(0, 0, -1, 0);
    __syncthreads();
    if (t < 256 && h[t]) atomicAdd(&dcount[t], h[t]);
}

__global__ __launch_bounds__(256) void k_dscan(const int* __restrict__ dcount,
                                               int* __restrict__ dcur) {
    __shared__ int ws[4];
    int t = threadIdx.x;
    int lane = t & 63, wv = t >> 6;
    int v = dcount[t];
    int x = v;
#pragma unroll
    for (int o = 1; o < 64; o <<= 1) {
        int u = __shfl_up(x, o, 64);
        if (lane >= o) x += u;
    }
    if (lane == 63) ws[wv] = x;
    __syncthreads();
    int add = 0;
    for (int w = 0; w < wv; ++w) add += ws[w];
    dcur[t] = add + x - v;  // exclusive scan -> working cursor
}

// counting-sort scatter, writes sinfo directly
__global__ __launch_bounds__(1024) void k_dscatter(const int* __restrict__ off,
                                                   const float* __restrict__ dinv,
                                                   int* __restrict__ dcur,
                                                   int4* __restrict__ sinfo, int n) {
    __shared__ int lcnt[256], lbase[256];
    int t = threadIdx.x;
    if (t < 256) lcnt[t] = 0;
    __syncthreads();
    int i = blockIdx.x * 1024 + t;
    int d = 0, rank = 0, a = 0, dtrue = 0;
    if (i < n) {
        a = off[i];
        dtrue = off[i + 1] - a;
        d = min(dtrue, 255);
        rank = atomicAdd(&lcnt[d], 1);
    }
    __syncthreads();
    if (t < 256 && lcnt[t]) lbase[t] = atomicAdd(&dcur[t], lcnt[t]);
    __syncthreads();
    if (i < n) {
        int slot = lbase[d] + rank;
        sinfo[slot] = make_int4(a, dtrue, i, __float_as_int(dinv[i]));
    }
}

// ---------------- Pass A: LDS-staged bucket binning (256-node buckets) ----------------
// ebuf entry: (dstLocal<<24) | src   (src < 2^24, dstLocal < 256)
__global__ __launch_bounds__(256) void k_binA(const int* __restrict__ src,
                                              const int* __restrict__ dst,
                                              int* __restrict__ ebuf,
                                              int* __restrict__ bcur,
                                              int e, int nbuck) {
    __shared__ int cnt[NBMAX], startb[NBMAX], posb[NBMAX], gbase[NBMAX];
    __shared__ int stage[ACHUNK];
    __shared__ unsigned short stb[ACHUNK];
    int t = threadIdx.x;
    for (int cbase = blockIdx.x * ACHUNK; cbase < e; cbase += gridDim.x * ACHUNK) {
        int cval = min(ACHUNK, e - cbase);
        for (int i = t; i < nbuck; i += 256) { cnt[i] = 0; posb[i] = 0; }
        __syncthreads();
        int eb[8], es[8];
#pragma unroll
        for (int k = 0; k < 8; ++k) {
            int i = t + k * 256;
            if (i < cval) {
                int s = src[cbase + i];
                int d = dst[cbase + i];
                eb[k] = d >> 8;
                es[k] = s | ((d & 255) << 24);
                atomicAdd(&cnt[eb[k]], 1);
            } else eb[k] = -1;
        }
        __syncthreads();
        if (t == 0) {
            int r = 0;
            for (int b2 = 0; b2 < nbuck; ++b2) { startb[b2] = r; r += cnt[b2]; }
        }
        __syncthreads();
        for (int i = t; i < nbuck; i += 256)
            if (cnt[i] > 0) gbase[i] = atomicAdd(&bcur[i], cnt[i]);
#pragma unroll
        for (int k = 0; k < 8; ++k)
            if (eb[k] >= 0) {
                int idx = startb[eb[k]] + atomicAdd(&posb[eb[k]], 1);
                stage[idx] = es[k];
                stb[idx] = (unsigned short)eb[k];
            }
        __syncthreads();
        for (int i = t; i < cval; i += 256) {
            int b2 = stb[i];
            ebuf[gbase[b2] + (i - startb[b2])] = stage[i];
        }
        __syncthreads();
    }
}

// ---------------- Pass B: per-bucket node hist + scan -> offs/dinv + mirror write, CSR scatter ----
__global__ __launch_bounds__(256) void k_binB(const int* __restrict__ ebuf,
                                              const int* __restrict__ bbase,
                                              const float* __restrict__ x,
                                              int* __restrict__ offs,
                                              float* __restrict__ dinv,
                                              __half* __restrict__ mA,
                                              int* __restrict__ csr, int n) {
    __shared__ int cnt[256], cur[256], ws[4];
    __shared__ float sdinv[256];
    int b = blockIdx.x;
    int base = b << 8;
    int nn = min(256, n - base);
    int t = threadIdx.x;
    int e0 = bbase[b], e1 = bbase[b + 1];
    cnt[t] = 0;
    __syncthreads();
    for (int i = e0 + t; i < e1; i += 256)
        atomicAdd(&cnt[((unsigned)ebuf[i]) >> 24], 1);
    __syncthreads();
    int v = cnt[t];
    int lane = t & 63, wv = t >> 6;
    int x2 = v;
#pragma unroll
    for (int o = 1; o < 64; o <<= 1) {
        int u = __shfl_up(x2, o, 64);
        if (lane >= o) x2 += u;
    }
    if (lane == 63) ws[wv] = x2;
    __syncthreads();
    int add = 0;
    for (int w = 0; w < wv; ++w) add += ws[w];
    int excl = add + x2 - v;
    float dv = rsqrtf((float)v + 1.0f);  // +1 self-loop
    if (t < nn) {
        offs[base + t] = e0 + excl;
        dinv[base + t] = dv;
    }
    sdinv[t] = dv;
    cur[t] = e0 + excl;
    __syncthreads();
    const int tot = nn * 64;
    const size_t gbase2 = (size_t)base * 64;
    for (int i = t; i < tot; i += 256) {
        float val = x[gbase2 + i] * sdinv[i >> 6];
        mA[gbase2 + i] = __float2half_rn(val);
    }
    for (int i = e0 + t; i < e1; i += 256) {
        int packed = ebuf[i];
        int dl = ((unsigned)packed) >> 24;
        int pos = atomicAdd(&cur[dl], 1);
        csr[pos] = packed & 0x00FFFFFF;
    }
}

// ======== shared device pieces (used by both coop and fallback paths) ========
// gather one tile (16 nodes) -> writes agg(fp16) and accumulates BN stats
static __device__ __forceinline__ void gather_tile(
    const int4* __restrict__ sinfo, const int* __restrict__ csr,
    const uint4* __restrict__ mrow4, const f16x8 bfr[2][4], const float bias[4],
    __half* __restrict__ agg, int tile, int n, int lane, int g, int ln,
    float s_acc[4], float q_acc[4]) {
    const int4 si = sinfo[tile * 16 + ln];
    const int a = si.x, deg = si.y, node = si.z;
    const float dd = __int_as_float(si.w);
    const int row_self = (node >= 0) ? node : n;

    int md = deg;
#pragma unroll
    for (int o = 1; o < 64; o <<= 1) md = max(md, __shfl_xor(md, o, 64));

    float acc[2][8];
#pragma unroll
    for (int kt = 0; kt < 2; ++kt)
#pragma unroll
        for (int j = 0; j < 8; ++j) acc[kt][j] = 0.f;

    {   // self row
        const uint4* rp = mrow4 + ((size_t)row_self << 3) + g;
        uint4 v0 = rp[0], v1 = rp[4];
        acc_u4(acc[0], v0);
        acc_u4(acc[1], v1);
    }
    int ecur[4];
#pragma unroll
    for (int k = 0; k < 4; ++k) ecur[k] = (k < deg) ? csr[a + k] : n;
    for (int i = 0; i < md; i += 4) {
        int enx[4];
#pragma unroll
        for (int k = 0; k < 4; ++k) enx[k] = (i + 4 + k < deg) ? csr[a + i + 4 + k] : n;
        uint4 v[4][2];
#pragma unroll
        for (int r = 0; r < 4; ++r) {
            const uint4* rp = mrow4 + ((size_t)ecur[r] << 3) + g;
            v[r][0] = rp[0];
            v[r][1] = rp[4];
        }
#pragma unroll
        for (int r = 0; r < 4; ++r) {
            acc_u4(acc[0], v[r][0]);
            acc_u4(acc[1], v[r][1]);
        }
#pragma unroll
        for (int k = 0; k < 4; ++k) ecur[k] = enx[k];
    }

    f32x4 c[4];
#pragma unroll
    for (int nt = 0; nt < 4; ++nt) c[nt] = (f32x4){0.f, 0.f, 0.f, 0.f};
#pragma unroll
    for (int kt = 0; kt < 2; ++kt) {
        f16x8 ah, ar;
#pragma unroll
        for (int j = 0; j < 8; ++j) {
            float v = acc[kt][j] * dd;
            _Float16 h = (_Float16)v;
            ah[j] = h;
            ar[j] = (_Float16)(v - (float)h);
        }
#pragma unroll
        for (int nt = 0; nt < 4; ++nt) {
            c[nt] = __builtin_amdgcn_mfma_f32_16x16x32_f16(ah, bfr[kt][nt], c[nt], 0, 0, 0);
            c[nt] = __builtin_amdgcn_mfma_f32_16x16x32_f16(ar, bfr[kt][nt], c[nt], 0, 0, 0);
        }
    }

    int prow[4];
#pragma unroll
    for (int i = 0; i < 4; ++i) prow[i] = __shfl(node, 4 * g + i, 64);
#pragma unroll
    for (int nt = 0; nt < 4; ++nt) {
#pragma unroll
        for (int i = 0; i < 4; ++i) {
            if (prow[i] >= 0) {
                float v = c[nt][i] + bias[nt];
                agg[(size_t)prow[i] * 64 + 16 * nt + ln] = __float2half_rn(v);
                s_acc[nt] += v;
                q_acc[nt] += v * v;
            }
        }
    }
}

// bn row transform
static __device__ __forceinline__ void bn_row(
    const __half* __restrict__ agg, const __half* __restrict__ res,
    __half* __restrict__ gout, const float* __restrict__ dinv,
    float mu_c, float bscale, float bshift, float lg, float lb,
    int r, int lane, int has_res, int scale_out) {
    float dd = dinv[r];
    float xx = __half2float(agg[(size_t)r * 64 + lane]);
    float hb = (xx - mu_c) * bscale + bshift;
    if (has_res) hb += __half2float(res[(size_t)r * 64 + lane]) * (1.0f / dd);
    float ssum = hb;
#pragma unroll
    for (int off = 32; off; off >>= 1) ssum += __shfl_xor(ssum, off, 64);
    float rmu = ssum * (1.f / 64.f);
    float d = hb - rmu;
    float vs = d * d;
#pragma unroll
    for (int off = 32; off; off >>= 1) vs += __shfl_xor(vs, off, 64);
    float rvar = vs * (1.f / 64.f);
    float lnv = d * rsqrtf(rvar + EPSV) * lg + lb;
    float gl = gelu_exact(lnv);
    float outv = scale_out ? gl * dd : gl;
    gout[(size_t)r * 64 + lane] = __float2half_rn(outv);
}

// ---------------- fused 3-layer cooperative kernel ----------------
__global__ __launch_bounds__(256, 4) void k_layers(
    const int4* __restrict__ sinfo, const int* __restrict__ csr,
    const float* __restrict__ convW, const float* __restrict__ convB,
    __half* __restrict__ m16A, __half* __restrict__ m16B,
    __half* __restrict__ agg, float* __restrict__ gstats,
    const float* __restrict__ dinv,
    const float* __restrict__ bn_g, const float* __restrict__ bn_b,
    const float* __restrict__ ln_g, const float* __restrict__ ln_b,
    const int* __restrict__ bnd,
    const float* __restrict__ W1, const float* __restrict__ b1,
    const float* __restrict__ ln1g, const float* __restrict__ ln1b,
    const float* __restrict__ W2, const float* __restrict__ b2,
    const float* __restrict__ ln2g, const float* __restrict__ ln2b,
    const float* __restrict__ W3, const float* __restrict__ b3,
    float* __restrict__ out, int n, int G) {
    cg::grid_group grid = cg::this_grid();
    __shared__ float smem[896];
    const int t = threadIdx.x;
    const int lane = t & 63, wv = t >> 6;
    const int g = lane >> 4, ln = lane & 15;
    const int ntiles = (n + 15) >> 4;
    const int NW = gridDim.x << 2;

    for (int l = 0; l < 3; ++l) {
        const __half* gin = (l == 1) ? m16B : m16A;
        __half* gout = (l == 1) ? m16A : m16B;
        const uint4* mrow4 = (const uint4*)gin;
        const float* W = convW + (size_t)l * 4096;
        float* gstat = gstats + (size_t)l * NSLICE * 128;

        // ---- phase A: gather + MFMA -> agg + BN stats ----
        f16x8 bfr[2][4];
#pragma unroll
        for (int kt = 0; kt < 2; ++kt)
#pragma unroll
            for (int nt = 0; nt < 4; ++nt) {
                f16x8 h;
#pragma unroll
                for (int j = 0; j < 8; ++j)
                    h[j] = (_Float16)W[(32 * kt + 8 * g + j) * 64 + 16 * nt + ln];
                bfr[kt][nt] = h;
            }
        const float bias[4] = {convB[l * 64 + ln], convB[l * 64 + 16 + ln],
                               convB[l * 64 + 32 + ln], convB[l * 64 + 48 + ln]};
        float* sred = smem;
        if (t < 128) sred[t] = 0.f;
        __syncthreads();

        float s_acc[4] = {0.f, 0.f, 0.f, 0.f}, q_acc[4] = {0.f, 0.f, 0.f, 0.f};
        for (int tile = blockIdx.x * 4 + wv; tile < ntiles; tile += NW)
            gather_tile(sinfo, csr, mrow4, bfr, bias, agg, tile, n, lane, g, ln, s_acc, q_acc);
#pragma unroll
        for (int nt = 0; nt < 4; ++nt) {
            s_acc[nt] += __shfl_xor(s_acc[nt], 16, 64);
            s_acc[nt] += __shfl_xor(s_acc[nt], 32, 64);
            q_acc[nt] += __shfl_xor(q_acc[nt], 16, 64);
            q_acc[nt] += __shfl_xor(q_acc[nt], 32, 64);
        }
        if (g == 0) {
#pragma unroll
            for (int nt = 0; nt < 4; ++nt) {
                atomicAdd(&sred[16 * nt + ln], s_acc[nt]);
                atomicAdd(&sred[64 + 16 * nt + ln], q_acc[nt]);
            }
        }
        __syncthreads();
        if (t < 64) {
            float* gs = gstat + (blockIdx.x & (NSLICE - 1)) * 128;
            fatomic_add(&gs[t], sred[t]);
            fatomic_add(&gs[64 + t], sred[64 + t]);
        }
        grid.sync();

        // ---- phase B: BN + residual + LN + GELU -> gout ----
        {
            float fs = 0.f, fq = 0.f;
#pragma unroll
            for (int s2 = 0; s2 < NSLICE; ++s2) {
                fs += gstat[s2 * 128 + lane];
                fq += gstat[s2 * 128 + 64 + lane];
            }
            float invN = 1.0f / (float)n;
            float mu_c = fs * invN;
            float var_c = fq * invN - mu_c * mu_c;
            float bscale = rsqrtf(var_c + EPSV) * bn_g[l * 64 + lane];
            float bshift = bn_b[l * 64 + lane];
            float lg = ln_g[l * 64 + lane], lb = ln_b[l * 64 + lane];
            const int has_res = (l > 0), scale_out = (l < 2);
            for (int r = blockIdx.x * 4 + wv; r < n; r += NW)
                bn_row(agg, gin, gout, dinv, mu_c, bscale, bshift, lg, lb, r, lane,
                       has_res, scale_out);
        }
        grid.sync();
    }

    // ---- pool + MLP head (blocks 0..G-1; h = m16B) ----
    if (blockIdx.x < (unsigned)G) {
        const __half* h = m16B;
        int gph = blockIdx.x;
        float* ss = smem;
        float* sm = smem + 256;
        float* zl = smem + 512;
        float* h1 = smem + 704;
        float* red = smem + 832;
        int s0 = bnd[gph], e0 = bnd[gph + 1];
        float s = 0.f, mx = -INFINITY;
        for (int i = s0 + wv; i < e0; i += 4) {
            float v = __half2float(h[(size_t)i * 64 + lane]);
            s += v;
            mx = fmaxf(mx, v);
        }
        ss[t] = s;
        sm[t] = mx;
        __syncthreads();
        if (t < 64) {
            float fs = ss[t] + ss[t + 64] + ss[t + 128] + ss[t + 192];
            float fm = fmaxf(fmaxf(sm[t], sm[t + 64]), fmaxf(sm[t + 128], sm[t + 192]));
            float cntf = (float)(e0 - s0);
            float mean = fs / fmaxf(cntf, 1.0f);
            if (e0 == s0) fm = 0.f;
            zl[t] = mean;
            zl[64 + t] = fm;
            zl[128 + t] = fs;
        }
        __syncthreads();
        float acc = 0.f;
        if (t < 128) {
            acc = b1[t];
            for (int k = 0; k < 192; ++k) acc += zl[k] * W1[k * 128 + t];
        }
        float s1 = acc;
#pragma unroll
        for (int off = 32; off; off >>= 1) s1 += __shfl_xor(s1, off, 64);
        if (lane == 0 && wv < 2) red[wv] = s1;
        __syncthreads();
        float mu = (red[0] + red[1]) * (1.f / 128.f);
        float d = acc - mu;
        float q = d * d;
#pragma unroll
        for (int off = 32; off; off >>= 1) q += __shfl_xor(q, off, 64);
        __syncthreads();
        if (lane == 0 && wv < 2) red[wv] = q;
        __syncthreads();
        float var = (red[0] + red[1]) * (1.f / 128.f);
        if (t < 128) {
            float lnv = d * rsqrtf(var + EPSV) * ln1g[t] + ln1b[t];
            h1[t] = gelu_exact(lnv);
        }
        __syncthreads();
        if (t < 64) {
            float acc2 = b2[t];
            for (int k = 0; k < 128; ++k) acc2 += h1[k] * W2[k * 64 + t];
            float s2 = acc2;
#pragma unroll
            for (int off = 32; off; off >>= 1) s2 += __shfl_xor(s2, off, 64);
            float mu2 = s2 * (1.f / 64.f);
            float d2 = acc2 - mu2;
            float q2 = d2 * d2;
#pragma unroll
            for (int off = 32; off; off >>= 1) q2 += __shfl_xor(q2, off, 64);
            float var2 = q2 * (1.f / 64.f);
            float l2 = d2 * rsqrtf(var2 + EPSV) * ln2g[t] + ln2b[t];
            float g2 = gelu_exact(l2);
            float p = g2 * W3[t];
#pragma unroll
            for (int off = 32; off; off >>= 1) p += __shfl_xor(p, off, 64);
            if (t == 0) out[gph] = p + b3[0];
        }
    }
}

// ---------------- fallback standalone kernels (R8 path, proven 402us) ----------------
__global__ __launch_bounds__(256, 4) void k_gather_gemm(const int4* __restrict__ sinfo,
                                                        const int* __restrict__ csr,
                                                        const __half* __restrict__ m16,
                                                        const float* __restrict__ W,
                                                        const float* __restrict__ convB,
                                                        __half* __restrict__ agg,
                                                        float* __restrict__ gstat,
                                                        int n) {
    __shared__ float sred[128];
    const int t = threadIdx.x;
    const int lane = t & 63, wv = t >> 6;
    const int g = lane >> 4, ln = lane & 15;
    f16x8 bfr[2][4];
#pragma unroll
    for (int kt = 0; kt < 2; ++kt)
#pragma unroll
        for (int nt = 0; nt < 4; ++nt) {
            f16x8 h;
#pragma unroll
            for (int j = 0; j < 8; ++j)
                h[j] = (_Float16)W[(32 * kt + 8 * g + j) * 64 + 16 * nt + ln];
            bfr[kt][nt] = h;
        }
    const float bias[4] = {convB[ln], convB[16 + ln], convB[32 + ln], convB[48 + ln]};
    if (t < 128) sred[t] = 0.f;
    __syncthreads();
    const int ntiles = (n + 15) >> 4;
    const int tile = blockIdx.x * 4 + wv;
    float s_acc[4] = {0.f, 0.f, 0.f, 0.f}, q_acc[4] = {0.f, 0.f, 0.f, 0.f};
    if (tile < ntiles)
        gather_tile(sinfo, csr, (const uint4*)m16, bfr, bias, agg, tile, n, lane, g, ln,
                    s_acc, q_acc);
#pragma unroll
    for (int nt = 0; nt < 4; ++nt) {
        s_acc[nt] += __shfl_xor(s_acc[nt], 16, 64);
        s_acc[nt] += __shfl_xor(s_acc[nt], 32, 64);
        q_acc[nt] += __shfl_xor(q_acc[nt], 16, 64);
        q_acc[nt] += __shfl_xor(q_acc[nt], 32, 64);
    }
    if (g == 0) {
#pragma unroll
        for (int nt = 0; nt < 4; ++nt) {
            atomicAdd(&sred[16 * nt + ln], s_acc[nt]);
            atomicAdd(&sred[64 + 16 * nt + ln], q_acc[nt]);
        }
    }
    __syncthreads();
    if (t < 64) {
        float* gs = gstat + (blockIdx.x & (NSLICE - 1)) * 128;
        fatomic_add(&gs[t], sred[t]);
        fatomic_add(&gs[64 + t], sred[64 + t]);
    }
}

__global__ __launch_bounds__(256) void k_bn_ln_gelu(const __half* __restrict__ agg,
                                                    const __half* __restrict__ m16res,
                                                    const float* __restrict__ gstat,
                                                    const float* __restrict__ dinv,
                                                    const float* __restrict__ bng,
                                                    const float* __restrict__ bnb,
                                                    const float* __restrict__ lng,
                                                    const float* __restrict__ lnb,
                                                    __half* __restrict__ m16out,
                                                    int n, int has_res, int scale_out) {
    int t = threadIdx.x;
    int lane = t & 63, wv = t >> 6;
    float fs = 0.f, fq = 0.f;
#pragma unroll
    for (int s = 0; s < NSLICE; ++s) {
        fs += gstat[s * 128 + lane];
        fq += gstat[s * 128 + 64 + lane];
    }
    float invN = 1.0f / (float)n;
    float mu_c = fs * invN;
    float var_c = fq * invN - mu_c * mu_c;
    float bscale = rsqrtf(var_c + EPSV) * bng[lane];
    float bshift = bnb[lane];
    float lg = lng[lane], lb = lnb[lane];
    for (int r = blockIdx.x * 4 + wv; r < n; r += gridDim.x * 4)
        bn_row(agg, m16res, m16out, dinv, mu_c, bscale, bshift, lg, lb, r, lane,
               has_res, scale_out);
}

__global__ __launch_bounds__(256) void k_poolhead(const __half* __restrict__ h,
                                                  const int* __restrict__ bnd,
                                                  const float* __restrict__ W1, const float* __restrict__ b1,
                                                  const float* __restrict__ ln1g, const float* __restrict__ ln1b,
                                                  const float* __restrict__ W2, const float* __restrict__ b2,
                                                  const float* __restrict__ ln2g, const float* __restrict__ ln2b,
                                                  const float* __restrict__ W3, const float* __restrict__ b3,
                                                  float* __restrict__ out) {
    int g = blockIdx.x;
    int t = threadIdx.x;
    int lane = t & 63, wv = t >> 6;
    __shared__ float ss[256], sm[256], zl[192], h1[128], red[2];
    int s0 = bnd[g], e0 = bnd[g + 1];
    float s = 0.f, mx = -INFINITY;
    for (int i = s0 + wv; i < e0; i += 4) {
        float v = __half2float(h[(size_t)i * 64 + lane]);
        s += v;
        mx = fmaxf(mx, v);
    }
    ss[t] = s;
    sm[t] = mx;
    __syncthreads();
    if (t < 64) {
        float fs = ss[t] + ss[t + 64] + ss[t + 128] + ss[t + 192];
        float fm = fmaxf(fmaxf(sm[t], sm[t + 64]), fmaxf(sm[t + 128], sm[t + 192]));
        float cntf = (float)(e0 - s0);
        float mean = fs / fmaxf(cntf, 1.0f);
        if (e0 == s0) fm = 0.f;
        zl[t] = mean;
        zl[64 + t] = fm;
        zl[128 + t] = fs;
    }
    __syncthreads();
    float acc = 0.f;
    if (t < 128) {
        acc = b1[t];
        for (int k = 0; k < 192; ++k) acc += zl[k] * W1[k * 128 + t];
    }
    float s1 = acc;
#pragma unroll
    for (int off = 32; off; off >>= 1) s1 += __shfl_xor(s1, off, 64);
    if (lane == 0 && wv < 2) red[wv] = s1;
    __syncthreads();
    float mu = (red[0] + red[1]) * (1.f / 128.f);
    float d = acc - mu;
    float q = d * d;
#pragma unroll
    for (int off = 32; off; off >>= 1) q += __shfl_xor(q, off, 64);
    __syncthreads();
    if (lane == 0 && wv < 2) red[wv] = q;
    __syncthreads();
    float var = (red[0] + red[1]) * (1.f / 128.f);
    if (t < 128) {
        float lnv = d * rsqrtf(var + EPSV) * ln1g[t] + ln1b[t];
        h1[t] = gelu_exact(lnv);
    }
    __syncthreads();
    if (t < 64) {
        float acc2 = b2[t];
        for (int k = 0; k < 128; ++k) acc2 += h1[k] * W2[k * 64 + t];
        float s2 = acc2;
#pragma unroll
        for (int off = 32; off; off >>= 1) s2 += __shfl_xor(s2, off, 64);
        float mu2 = s2 * (1.f / 64.f);
        float d2 = acc2 - mu2;
        float q2 = d2 * d2;
#pragma unroll
        for (int off = 32; off; off >>= 1) q2 += __shfl_xor(q2, off, 64);
        float var2 = q2 * (1.f / 64.f);
        float l2 = d2 * rsqrtf(var2 + EPSV) * ln2g[t] + ln2b[t];
        float g2 = gelu_exact(l2);
        float p = g2 * W3[t];
#pragma unroll
        for (int off = 32; off; off >>= 1) p += __shfl_xor(p, off, 64);
        if (t == 0) out[g] = p + b3[0];
    }
}

extern "C" void kernel_launch(void* const* d_in, const int* in_sizes, int n_in,
                              void* d_out, int out_size, void* d_ws, size_t ws_size,
                              hipStream_t stream) {
    const float* x      = (const float*)d_in[0];
    const int*   eidx   = (const int*)d_in[1];
    const int*   batch  = (const int*)d_in[2];
    const float* convW  = (const float*)d_in[3];
    const float* convB  = (const float*)d_in[4];
    const float* bn_g   = (const float*)d_in[5];
    const float* bn_b   = (const float*)d_in[6];
    const float* ln_g   = (const float*)d_in[7];
    const float* ln_b   = (const float*)d_in[8];
    const float* W1     = (const float*)d_in[9];
    const float* b1     = (const float*)d_in[10];
    const float* ln1g   = (const float*)d_in[11];
    const float* ln1b   = (const float*)d_in[12];
    const float* W2     = (const float*)d_in[13];
    const float* b2     = (const float*)d_in[14];
    const float* ln2g   = (const float*)d_in[15];
    const float* ln2b   = (const float*)d_in[16];
    const float* W3     = (const float*)d_in[17];
    const float* b3     = (const float*)d_in[18];
    float* out = (float*)d_out;

    const int N = in_sizes[0] / DD;
    const int E = in_sizes[1] / 2;
    const int G = out_size;
    const int* esrc = eidx;
    const int* edst = eidx + E;

    char* ws = (char*)d_ws;
    size_t off_b = 0;
    auto alloc = [&](size_t bytes) {
        size_t p = off_b;
        off_b = (off_b + bytes + 255) & ~(size_t)255;
        return (void*)(ws + p);
    };
    const int ntiles = (N + 15) / 16;

    // stats region first (contiguous -> single memset): gstats | dcount | bucketCnt
    float*  gstats = (float*)alloc((size_t)3 * NSLICE * 128 * 4);
    int*    dcount = (int*)alloc(256 * 4);
    int*    bucketCnt = (int*)alloc((size_t)NBMAX * 4);
    const size_t zero_bytes = 3 * NSLICE * 128 * 4 + 1024 + 1792;
    int*    offs   = (int*)alloc((size_t)(N + 1) * 4);
    float*  dinv   = (float*)alloc((size_t)N * 4);
    int*    csr    = (int*)alloc((size_t)E * 4);
    int*    ebuf   = (int*)alloc((size_t)E * 4);
    __half* m16A   = (__half*)alloc((size_t)(N + 1) * DD * 2);
    __half* m16B   = (__half*)alloc((size_t)(N + 1) * DD * 2);
    __half* aggbuf = (__half*)alloc((size_t)N * DD * 2);
    int4*   sinfo  = (int4*)alloc((size_t)ntiles * 16 * 16);
    int*    dcur   = (int*)alloc(256 * 4);
    int*    bnd    = (int*)alloc((size_t)(G + 1) * 4);
    int*    bbase  = (int*)alloc((size_t)(NBMAX + 1) * 4);
    int*    bcur   = (int*)alloc(((size_t)(N + 255) / 256) * 4);
    (void)ws_size; (void)n_in;

    const int nbuck = (N + 255) / 256;
    const int nb = (N + 1023) / 1024;

    // ---- CSR build + planning ----
    hipMemsetAsync(gstats, 0, zero_bytes, stream);
    k_bcount<<<(E + 8191) / 8192, 1024, 0, stream>>>(edst, bucketCnt, E, nbuck);
    k_bscan2<<<1, 512, 0, stream>>>(bucketCnt, bbase, bcur, offs, nbuck, E, N);
    k_binA<<<(E + ACHUNK - 1) / ACHUNK, 256, 0, stream>>>(esrc, edst, ebuf, bcur, E, nbuck);
    k_binB<<<nbuck, 256, 0, stream>>>(ebuf, bbase, x, offs, dinv, m16A, csr, N);
    k_dhist<<<nb, 1024, 0, stream>>>(offs, dcount, batch, bnd, m16A, m16B, sinfo, N, G, ntiles);
    k_dscan<<<1, 256, 0, stream>>>(dcount, dcur);
    k_dscatter<<<nb, 1024, 0, stream>>>(offs, dinv, dcur, sinfo, N);

    // ---- fused 3-layer + pool/head cooperative kernel (with R8 fallback) ----
    int Nv = N, Gv = G;
    void* args[] = {
        (void*)&sinfo, (void*)&csr, (void*)&convW, (void*)&convB,
        (void*)&m16A, (void*)&m16B, (void*)&aggbuf, (void*)&gstats,
        (void*)&dinv, (void*)&bn_g, (void*)&bn_b, (void*)&ln_g, (void*)&ln_b,
        (void*)&bnd, (void*)&W1, (void*)&b1, (void*)&ln1g, (void*)&ln1b,
        (void*)&W2, (void*)&b2, (void*)&ln2g, (void*)&ln2b,
        (void*)&W3, (void*)&b3, (void*)&out, (void*)&Nv, (void*)&Gv};
    hipError_t cerr = hipLaunchCooperativeKernel((void*)k_layers, dim3(CGBLOCKS),
                                                 dim3(256), args, 0, stream);
    if (cerr != hipSuccess) {
        // fallback: separate dispatches (R8 path, measured 402us)
        const int gblocks = (ntiles + 3) / 4;
        __half* gin[3]  = {m16A, m16B, m16A};
        __half* gout[3] = {m16B, m16A, m16B};
        for (int l = 0; l < 3; ++l) {
            float* gstat = gstats + (size_t)l * NSLICE * 128;
            k_gather_gemm<<<gblocks, 256, 0, stream>>>(sinfo, csr, (const __half*)gin[l],
                                                       convW + (size_t)l * DD * DD,
                                                       convB + l * DD, aggbuf, gstat, N);
            k_bn_ln_gelu<<<2048, 256, 0, stream>>>(aggbuf, gin[l], gstat, dinv,
                                                   bn_g + l * DD, bn_b + l * DD,
                                                   ln_g + l * DD, ln_b + l * DD,
                                                   gout[l], N, l > 0 ? 1 : 0, l < 2 ? 1 : 0);
        }
        k_poolhead<<<G, 256, 0, stream>>>(m16B, bnd, W1, b1, ln1g, ln1b,
                                          W2, b2, ln2g, ln2b, W3, b3, out);
    }
}

// Round 11
// 401.802 us; speedup vs baseline: 2.8872x; 2.8872x over previous
//
#include <hip/hip_runtime.h>
#include <hip/hip_bf16.h>
#include <hip/hip_fp16.h>

#define DD 64
#define EPSV 1e-5f
#define NSLICE 16

typedef __attribute__((ext_vector_type(4))) _Float16 f16x4;
typedef __attribute__((ext_vector_type(8))) _Float16 f16x8;
typedef __attribute__((ext_vector_type(4))) float f32x4;

static __device__ __forceinline__ float fatomic_add(float* p, float v) {
#if defined(__HIP_DEVICE_COMPILE__)
    return unsafeAtomicAdd(p, v);
#else
    return 0.f;
#endif
}

static __device__ __forceinline__ float gelu_exact(float x) {
    return 0.5f * x * (1.0f + erff(x * 0.70710678118654752f));
}

// accumulate 8 halfs (uint4) into 8 fp32 accumulators
static __device__ __forceinline__ void acc_u4(float* a8, uint4 v) {
    const __half2* hp = reinterpret_cast<const __half2*>(&v);
#pragma unroll
    for (int p = 0; p < 4; ++p) {
        float2 f = __half22float2(hp[p]);
        a8[2 * p] += f.x;
        a8[2 * p + 1] += f.y;
    }
}

#define ACHUNK 2048
#define NBMAX 400

// ---------------- bucket-level edge count ----------------
__global__ __launch_bounds__(1024) void k_bcount(const int* __restrict__ dst,
                                                 int* __restrict__ bucketCnt,
                                                 int e, int nbuck) {
    __shared__ int h[NBMAX];
    int t = threadIdx.x;
    for (int i = t; i < nbuck; i += 1024) h[i] = 0;
    __syncthreads();
    int base = blockIdx.x * 8192;
#pragma unroll
    for (int k = 0; k < 8; ++k) {
        int i = base + k * 1024 + t;
        if (i < e) atomicAdd(&h[dst[i] >> 8], 1);
    }
    __syncthreads();
    for (int i = t; i < nbuck; i += 1024)
        if (h[i]) atomicAdd(&bucketCnt[i], h[i]);
}

// scan bucket counts -> bbase (exclusive), seed binA cursors, write offs[n]
__global__ __launch_bounds__(512) void k_bscan2(const int* __restrict__ bucketCnt,
                                                int* __restrict__ bbase,
                                                int* __restrict__ bcur,
                                                int* __restrict__ offs,
                                                int nbuck, int etotal, int n) {
    __shared__ int ws[8];
    int t = threadIdx.x, lane = t & 63, wv = t >> 6;
    int v = (t < nbuck) ? bucketCnt[t] : 0;
    int x = v;
#pragma unroll
    for (int o = 1; o < 64; o <<= 1) {
        int u = __shfl_up(x, o, 64);
        if (lane >= o) x += u;
    }
    if (lane == 63) ws[wv] = x;
    __syncthreads();
    int add = 0;
    for (int w = 0; w < wv; ++w) add += ws[w];
    int excl = add + x - v;
    if (t < nbuck) {
        bbase[t] = excl;
        bcur[t] = excl;
    }
    if (t == 0) {
        bbase[nbuck] = etotal;
        offs[n] = etotal;
    }
}

// ---------------- degree hist + bnd + zero rows + sinfo tail ----------------
__global__ __launch_bounds__(1024) void k_dhist(const int* __restrict__ off,
                                                int* __restrict__ dcount,
                                                const int* __restrict__ batch,
                                                int* __restrict__ bnd,
                                                __half* __restrict__ mA,
                                                __half* __restrict__ mB,
                                                int4* __restrict__ sinfo,
                                                int n, int g, int ntiles) {
    __shared__ int h[256];
    int t = threadIdx.x;
    if (t < 256) h[t] = 0;
    __syncthreads();
    int i = blockIdx.x * 1024 + t;
    if (i < n) {
        int d = min(off[i + 1] - off[i], 255);
        atomicAdd(&h[d], 1);
        int b = batch[i];
        if (i == 0)
            for (int q = 0; q <= b; ++q) bnd[q] = 0;
        else {
            int pb = batch[i - 1];
            for (int q = pb + 1; q <= b; ++q) bnd[q] = i;
        }
        if (i == n - 1)
            for (int q = b + 1; q <= g; ++q) bnd[q] = n;
    }
    if (blockIdx.x == 0 && t < 64) {  // dummy zero row at index n (gather tail identity)
        mA[(size_t)n * 64 + t] = __float2half_rn(0.f);
        mB[(size_t)n * 64 + t] = __float2half_rn(0.f);
    }
    int pad = ntiles * 16 - n;
    if (blockIdx.x == 0 && t < pad) sinfo[n + t] = make_int4(0, 0, -1, 0);
    __syncthreads();
    if (t < 256 && h[t]) atomicAdd(&dcount[t], h[t]);
}

__global__ __launch_bounds__(256) void k_dscan(const int* __restrict__ dcount,
                                               int* __restrict__ dcur) {
    __shared__ int ws[4];
    int t = threadIdx.x;
    int lane = t & 63, wv = t >> 6;
    int v = dcount[t];
    int x = v;
#pragma unroll
    for (int o = 1; o < 64; o <<= 1) {
        int u = __shfl_up(x, o, 64);
        if (lane >= o) x += u;
    }
    if (lane == 63) ws[wv] = x;
    __syncthreads();
    int add = 0;
    for (int w = 0; w < wv; ++w) add += ws[w];
    dcur[t] = add + x - v;  // exclusive scan -> working cursor
}

// counting-sort scatter, writes sinfo directly (perm eliminated)
__global__ __launch_bounds__(1024) void k_dscatter(const int* __restrict__ off,
                                                   const float* __restrict__ dinv,
                                                   int* __restrict__ dcur,
                                                   int4* __restrict__ sinfo, int n) {
    __shared__ int lcnt[256], lbase[256];
    int t = threadIdx.x;
    if (t < 256) lcnt[t] = 0;
    __syncthreads();
    int i = blockIdx.x * 1024 + t;
    int d = 0, rank = 0, a = 0, dtrue = 0;
    if (i < n) {
        a = off[i];
        dtrue = off[i + 1] - a;
        d = min(dtrue, 255);
        rank = atomicAdd(&lcnt[d], 1);
    }
    __syncthreads();
    if (t < 256 && lcnt[t]) lbase[t] = atomicAdd(&dcur[t], lcnt[t]);
    __syncthreads();
    if (i < n) {
        int slot = lbase[d] + rank;
        sinfo[slot] = make_int4(a, dtrue, i, __float_as_int(dinv[i]));
    }
}

// ---------------- Pass A: LDS-staged bucket binning (256-node buckets) ----------------
// ebuf entry: (dstLocal<<24) | src   (src < 2^24, dstLocal < 256)
__global__ __launch_bounds__(256) void k_binA(const int* __restrict__ src,
                                              const int* __restrict__ dst,
                                              int* __restrict__ ebuf,
                                              int* __restrict__ bcur,
                                              int e, int nbuck) {
    __shared__ int cnt[NBMAX], startb[NBMAX], posb[NBMAX], gbase[NBMAX];
    __shared__ int stage[ACHUNK];
    __shared__ unsigned short stb[ACHUNK];
    int t = threadIdx.x;
    for (int cbase = blockIdx.x * ACHUNK; cbase < e; cbase += gridDim.x * ACHUNK) {
        int cval = min(ACHUNK, e - cbase);
        for (int i = t; i < nbuck; i += 256) { cnt[i] = 0; posb[i] = 0; }
        __syncthreads();
        int eb[8], es[8];
#pragma unroll
        for (int k = 0; k < 8; ++k) {
            int i = t + k * 256;
            if (i < cval) {
                int s = src[cbase + i];
                int d = dst[cbase + i];
                eb[k] = d >> 8;
                es[k] = s | ((d & 255) << 24);
                atomicAdd(&cnt[eb[k]], 1);
            } else eb[k] = -1;
        }
        __syncthreads();
        if (t == 0) {
            int r = 0;
            for (int b2 = 0; b2 < nbuck; ++b2) { startb[b2] = r; r += cnt[b2]; }
        }
        __syncthreads();
        for (int i = t; i < nbuck; i += 256)
            if (cnt[i] > 0) gbase[i] = atomicAdd(&bcur[i], cnt[i]);
#pragma unroll
        for (int k = 0; k < 8; ++k)
            if (eb[k] >= 0) {
                int idx = startb[eb[k]] + atomicAdd(&posb[eb[k]], 1);
                stage[idx] = es[k];
                stb[idx] = (unsigned short)eb[k];
            }
        __syncthreads();
        for (int i = t; i < cval; i += 256) {
            int b2 = stb[i];
            ebuf[gbase[b2] + (i - startb[b2])] = stage[i];
        }
        __syncthreads();
    }
}

// ---------------- Pass B: per-bucket node hist + scan -> offs/dinv + mirror write, CSR scatter ----
__global__ __launch_bounds__(256) void k_binB(const int* __restrict__ ebuf,
                                              const int* __restrict__ bbase,
                                              const float* __restrict__ x,
                                              int* __restrict__ offs,
                                              float* __restrict__ dinv,
                                              __half* __restrict__ mA,
                                              int* __restrict__ csr, int n) {
    __shared__ int cnt[256], cur[256], ws[4];
    __shared__ float sdinv[256];
    int b = blockIdx.x;
    int base = b << 8;
    int nn = min(256, n - base);
    int t = threadIdx.x;
    int e0 = bbase[b], e1 = bbase[b + 1];
    cnt[t] = 0;
    __syncthreads();
    for (int i = e0 + t; i < e1; i += 256)
        atomicAdd(&cnt[((unsigned)ebuf[i]) >> 24], 1);
    __syncthreads();
    int v = cnt[t];
    int lane = t & 63, wv = t >> 6;
    int x2 = v;
#pragma unroll
    for (int o = 1; o < 64; o <<= 1) {
        int u = __shfl_up(x2, o, 64);
        if (lane >= o) x2 += u;
    }
    if (lane == 63) ws[wv] = x2;
    __syncthreads();
    int add = 0;
    for (int w = 0; w < wv; ++w) add += ws[w];
    int excl = add + x2 - v;
    float dv = rsqrtf((float)v + 1.0f);  // +1 self-loop
    if (t < nn) {
        offs[base + t] = e0 + excl;
        dinv[base + t] = dv;
    }
    sdinv[t] = dv;
    cur[t] = e0 + excl;
    __syncthreads();
    const int tot = nn * 64;
    const size_t gbase2 = (size_t)base * 64;
    for (int i = t; i < tot; i += 256) {
        float val = x[gbase2 + i] * sdinv[i >> 6];
        mA[gbase2 + i] = __float2half_rn(val);
    }
    for (int i = e0 + t; i < e1; i += 256) {
        int packed = ebuf[i];
        int dl = ((unsigned)packed) >> 24;
        int pos = atomicAdd(&cur[dl], 1);
        csr[pos] = packed & 0x00FFFFFF;
    }
}

// ---------------- fused: multi-stream fp16 gather -> MFMA row GEMM -> BN stats ----------------
// One-shot static (ONE 16-node tile per wave — R3/R10 twice proved any per-wave
// sequential tile loop collapses memory-level parallelism); degree-sorted sinfo
// => md ~= deg; agg stored fp16.
__global__ __launch_bounds__(256, 4) void k_gather_gemm(const int4* __restrict__ sinfo,
                                                        const int* __restrict__ csr,
                                                        const __half* __restrict__ m16,
                                                        const float* __restrict__ W,
                                                        const float* __restrict__ convB,
                                                        __half* __restrict__ agg,
                                                        float* __restrict__ gstat,  // NSLICE x 128
                                                        int n, int nzero) {
    __shared__ float sred[128];
    const int t = threadIdx.x;
    const int lane = t & 63, wv = t >> 6;
    const int g = lane >> 4, ln = lane & 15;

    // B fragments for 16x16x32_f16: bfr[kt][nt][j] = W[32kt+8g+j][16nt+ln]
    f16x8 bfr[2][4];
#pragma unroll
    for (int kt = 0; kt < 2; ++kt)
#pragma unroll
        for (int nt = 0; nt < 4; ++nt) {
            f16x8 h;
#pragma unroll
            for (int j = 0; j < 8; ++j)
                h[j] = (_Float16)W[(32 * kt + 8 * g + j) * 64 + 16 * nt + ln];
            bfr[kt][nt] = h;
        }
    const float bias[4] = {convB[ln], convB[16 + ln], convB[32 + ln], convB[48 + ln]};

    if (t < 128) sred[t] = 0.f;
    __syncthreads();

    const int ntiles = (n + 15) >> 4;
    const int tile = blockIdx.x * 4 + wv;
    float s_acc[4] = {0.f, 0.f, 0.f, 0.f}, q_acc[4] = {0.f, 0.f, 0.f, 0.f};
    const uint4* mrow4 = (const uint4*)m16;  // 8 uint4 per row; lane chunks at g, g+4

    if (tile < ntiles) {
        const int4 si = sinfo[tile * 16 + ln];  // coalesced; broadcast across g
        const int a = si.x, deg = si.y, node = si.z;
        const float dd = __int_as_float(si.w);
        const int row_self = (node >= 0) ? node : nzero;

        int md = deg;
#pragma unroll
        for (int o = 1; o < 64; o <<= 1) md = max(md, __shfl_xor(md, o, 64));

        float acc[2][8];
#pragma unroll
        for (int kt = 0; kt < 2; ++kt)
#pragma unroll
            for (int j = 0; j < 8; ++j) acc[kt][j] = 0.f;

        {   // self row
            const uint4* rp = mrow4 + ((size_t)row_self << 3) + g;
            uint4 v0 = rp[0], v1 = rp[4];
            acc_u4(acc[0], v0);
            acc_u4(acc[1], v1);
        }
        int ecur[4];
#pragma unroll
        for (int k = 0; k < 4; ++k) ecur[k] = (k < deg) ? csr[a + k] : nzero;
        for (int i = 0; i < md; i += 4) {
            int enx[4];
#pragma unroll
            for (int k = 0; k < 4; ++k) enx[k] = (i + 4 + k < deg) ? csr[a + i + 4 + k] : nzero;
            uint4 v[4][2];
#pragma unroll
            for (int r = 0; r < 4; ++r) {
                const uint4* rp = mrow4 + ((size_t)ecur[r] << 3) + g;
                v[r][0] = rp[0];
                v[r][1] = rp[4];
            }
#pragma unroll
            for (int r = 0; r < 4; ++r) {
                acc_u4(acc[0], v[r][0]);
                acc_u4(acc[1], v[r][1]);
            }
#pragma unroll
            for (int k = 0; k < 4; ++k) ecur[k] = enx[k];
        }

        // outer dinv scale; fp16 split A; 16x16x32 f16 MFMA, 2 K-steps, 4 N-tiles
        f32x4 c[4];
#pragma unroll
        for (int nt = 0; nt < 4; ++nt) c[nt] = (f32x4){0.f, 0.f, 0.f, 0.f};
#pragma unroll
        for (int kt = 0; kt < 2; ++kt) {
            f16x8 ah, ar;
#pragma unroll
            for (int j = 0; j < 8; ++j) {
                float v = acc[kt][j] * dd;
                _Float16 h = (_Float16)v;
                ah[j] = h;
                ar[j] = (_Float16)(v - (float)h);
            }
#pragma unroll
            for (int nt = 0; nt < 4; ++nt) {
                c[nt] = __builtin_amdgcn_mfma_f32_16x16x32_f16(ah, bfr[kt][nt], c[nt], 0, 0, 0);
                c[nt] = __builtin_amdgcn_mfma_f32_16x16x32_f16(ar, bfr[kt][nt], c[nt], 0, 0, 0);
            }
        }

        // D layout: c[nt][i] = out[slot = tile*16 + 4g + i][col = 16nt + ln].
        int prow[4];
#pragma unroll
        for (int i = 0; i < 4; ++i) prow[i] = __shfl(node, 4 * g + i, 64);
#pragma unroll
        for (int nt = 0; nt < 4; ++nt) {
#pragma unroll
            for (int i = 0; i < 4; ++i) {
                if (prow[i] >= 0) {
                    float v = c[nt][i] + bias[nt];
                    agg[(size_t)prow[i] * 64 + 16 * nt + ln] = __float2half_rn(v);
                    s_acc[nt] += v;
                    q_acc[nt] += v * v;
                }
            }
        }
    }

    // fold per-wave stats: across g groups, then LDS, then sliced global
#pragma unroll
    for (int nt = 0; nt < 4; ++nt) {
        s_acc[nt] += __shfl_xor(s_acc[nt], 16, 64);
        s_acc[nt] += __shfl_xor(s_acc[nt], 32, 64);
        q_acc[nt] += __shfl_xor(q_acc[nt], 16, 64);
        q_acc[nt] += __shfl_xor(q_acc[nt], 32, 64);
    }
    if (g == 0) {
#pragma unroll
        for (int nt = 0; nt < 4; ++nt) {
            atomicAdd(&sred[16 * nt + ln], s_acc[nt]);
            atomicAdd(&sred[64 + 16 * nt + ln], q_acc[nt]);
        }
    }
    __syncthreads();
    if (t < 64) {
        float* gs = gstat + (blockIdx.x & (NSLICE - 1)) * 128;
        fatomic_add(&gs[t], sred[t]);
        fatomic_add(&gs[64 + t], sred[64 + t]);
    }
}

// ---------------- BN + residual(fp16 mirror) + LN + GELU -> fp16 mirror only ----------------
__global__ __launch_bounds__(256) void k_bn_ln_gelu(const __half* __restrict__ agg,
                                                    const __half* __restrict__ m16res,
                                                    const float* __restrict__ gstat,  // NSLICE x 128
                                                    const float* __restrict__ dinv,
                                                    const float* __restrict__ bng,
                                                    const float* __restrict__ bnb,
                                                    const float* __restrict__ lng,
                                                    const float* __restrict__ lnb,
                                                    __half* __restrict__ m16out,
                                                    int n, int has_res, int scale_out) {
    int t = threadIdx.x;
    int lane = t & 63, wv = t >> 6;
    float fs = 0.f, fq = 0.f;
#pragma unroll
    for (int s = 0; s < NSLICE; ++s) {
        fs += gstat[s * 128 + lane];
        fq += gstat[s * 128 + 64 + lane];
    }
    float invN = 1.0f / (float)n;
    float mu_c = fs * invN;
    float var_c = fq * invN - mu_c * mu_c;
    float bscale = rsqrtf(var_c + EPSV) * bng[lane];
    float bshift = bnb[lane];
    float lg = lng[lane], lb = lnb[lane];
    for (int r = blockIdx.x * 4 + wv; r < n; r += gridDim.x * 4) {
        float dd = dinv[r];
        float x = __half2float(agg[(size_t)r * 64 + lane]);
        float hb = (x - mu_c) * bscale + bshift;
        if (has_res) hb += __half2float(m16res[(size_t)r * 64 + lane]) * (1.0f / dd);
        float ssum = hb;
#pragma unroll
        for (int off = 32; off; off >>= 1) ssum += __shfl_xor(ssum, off, 64);
        float rmu = ssum * (1.f / 64.f);
        float d = hb - rmu;
        float vs = d * d;
#pragma unroll
        for (int off = 32; off; off >>= 1) vs += __shfl_xor(vs, off, 64);
        float rvar = vs * (1.f / 64.f);
        float ln = d * rsqrtf(rvar + EPSV) * lg + lb;
        float g = gelu_exact(ln);
        float outv = scale_out ? g * dd : g;
        m16out[(size_t)r * 64 + lane] = __float2half_rn(outv);
    }
}

// ---------------- fused pooling + MLP head (one block per graph; z stays in LDS) ----------------
__global__ __launch_bounds__(256) void k_poolhead(const __half* __restrict__ h,
                                                  const int* __restrict__ bnd,
                                                  const float* __restrict__ W1, const float* __restrict__ b1,
                                                  const float* __restrict__ ln1g, const float* __restrict__ ln1b,
                                                  const float* __restrict__ W2, const float* __restrict__ b2,
                                                  const float* __restrict__ ln2g, const float* __restrict__ ln2b,
                                                  const float* __restrict__ W3, const float* __restrict__ b3,
                                                  float* __restrict__ out) {
    int g = blockIdx.x;
    int t = threadIdx.x;
    int lane = t & 63, wv = t >> 6;
    __shared__ float ss[256], sm[256], zl[192], h1[128], red[2];
    int s0 = bnd[g], e0 = bnd[g + 1];
    float s = 0.f, mx = -INFINITY;
    for (int i = s0 + wv; i < e0; i += 4) {
        float v = __half2float(h[(size_t)i * 64 + lane]);
        s += v;
        mx = fmaxf(mx, v);
    }
    ss[t] = s;
    sm[t] = mx;
    __syncthreads();
    if (t < 64) {
        float fs = ss[t] + ss[t + 64] + ss[t + 128] + ss[t + 192];
        float fm = fmaxf(fmaxf(sm[t], sm[t + 64]), fmaxf(sm[t + 128], sm[t + 192]));
        float cntf = (float)(e0 - s0);
        float mean = fs / fmaxf(cntf, 1.0f);
        if (e0 == s0) fm = 0.f;
        zl[t] = mean;
        zl[64 + t] = fm;
        zl[128 + t] = fs;
    }
    __syncthreads();
    float acc = 0.f;
    if (t < 128) {
        acc = b1[t];
        for (int k = 0; k < 192; ++k) acc += zl[k] * W1[k * 128 + t];
    }
    float s1 = acc;
#pragma unroll
    for (int off = 32; off; off >>= 1) s1 += __shfl_xor(s1, off, 64);
    if (lane == 0 && wv < 2) red[wv] = s1;
    __syncthreads();
    float mu = (red[0] + red[1]) * (1.f / 128.f);
    float d = acc - mu;
    float q = d * d;
#pragma unroll
    for (int off = 32; off; off >>= 1) q += __shfl_xor(q, off, 64);
    __syncthreads();
    if (lane == 0 && wv < 2) red[wv] = q;
    __syncthreads();
    float var = (red[0] + red[1]) * (1.f / 128.f);
    if (t < 128) {
        float lnv = d * rsqrtf(var + EPSV) * ln1g[t] + ln1b[t];
        h1[t] = gelu_exact(lnv);
    }
    __syncthreads();
    if (t < 64) {
        float acc2 = b2[t];
        for (int k = 0; k < 128; ++k) acc2 += h1[k] * W2[k * 64 + t];
        float s2 = acc2;
#pragma unroll
        for (int off = 32; off; off >>= 1) s2 += __shfl_xor(s2, off, 64);
        float mu2 = s2 * (1.f / 64.f);
        float d2 = acc2 - mu2;
        float q2 = d2 * d2;
#pragma unroll
        for (int off = 32; off; off >>= 1) q2 += __shfl_xor(q2, off, 64);
        float var2 = q2 * (1.f / 64.f);
        float l2 = d2 * rsqrtf(var2 + EPSV) * ln2g[t] + ln2b[t];
        float g2 = gelu_exact(l2);
        float p = g2 * W3[t];
#pragma unroll
        for (int off = 32; off; off >>= 1) p += __shfl_xor(p, off, 64);
        if (t == 0) out[g] = p + b3[0];
    }
}

extern "C" void kernel_launch(void* const* d_in, const int* in_sizes, int n_in,
                              void* d_out, int out_size, void* d_ws, size_t ws_size,
                              hipStream_t stream) {
    const float* x      = (const float*)d_in[0];
    const int*   eidx   = (const int*)d_in[1];
    const int*   batch  = (const int*)d_in[2];
    const float* convW  = (const float*)d_in[3];
    const float* convB  = (const float*)d_in[4];
    const float* bn_g   = (const float*)d_in[5];
    const float* bn_b   = (const float*)d_in[6];
    const float* ln_g   = (const float*)d_in[7];
    const float* ln_b   = (const float*)d_in[8];
    const float* W1     = (const float*)d_in[9];
    const float* b1     = (const float*)d_in[10];
    const float* ln1g   = (const float*)d_in[11];
    const float* ln1b   = (const float*)d_in[12];
    const float* W2     = (const float*)d_in[13];
    const float* b2     = (const float*)d_in[14];
    const float* ln2g   = (const float*)d_in[15];
    const float* ln2b   = (const float*)d_in[16];
    const float* W3     = (const float*)d_in[17];
    const float* b3     = (const float*)d_in[18];
    float* out = (float*)d_out;

    const int N = in_sizes[0] / DD;
    const int E = in_sizes[1] / 2;
    const int G = out_size;
    const int* esrc = eidx;
    const int* edst = eidx + E;

    char* ws = (char*)d_ws;
    size_t off_b = 0;
    auto alloc = [&](size_t bytes) {
        size_t p = off_b;
        off_b = (off_b + bytes + 255) & ~(size_t)255;
        return (void*)(ws + p);
    };
    const int ntiles = (N + 15) / 16;

    // stats region first (contiguous -> single memset): gstats | dcount | bucketCnt
    float*  gstats = (float*)alloc((size_t)3 * NSLICE * 128 * 4); // 24576 B
    int*    dcount = (int*)alloc(256 * 4);                         // 1024 B
    int*    bucketCnt = (int*)alloc((size_t)NBMAX * 4);            // 1600->1792 B
    const size_t zero_bytes = 3 * NSLICE * 128 * 4 + 1024 + 1792;
    int*    offs   = (int*)alloc((size_t)(N + 1) * 4);
    float*  dinv   = (float*)alloc((size_t)N * 4);
    int*    csr    = (int*)alloc((size_t)E * 4);
    int*    ebuf   = (int*)alloc((size_t)E * 4);
    __half* m16A   = (__half*)alloc((size_t)(N + 1) * DD * 2);
    __half* m16B   = (__half*)alloc((size_t)(N + 1) * DD * 2);
    __half* aggbuf = (__half*)alloc((size_t)N * DD * 2);
    int4*   sinfo  = (int4*)alloc((size_t)ntiles * 16 * 16);
    int*    dcur   = (int*)alloc(256 * 4);
    int*    bnd    = (int*)alloc((size_t)(G + 1) * 4);
    int*    bbase  = (int*)alloc((size_t)(NBMAX + 1) * 4);
    int*    bcur   = (int*)alloc(((size_t)(N + 255) / 256) * 4);
    (void)ws_size; (void)n_in;

    const int nbuck = (N + 255) / 256;
    const int nb = (N + 1023) / 1024;

    // ---- CSR build + planning ----
    hipMemsetAsync(gstats, 0, zero_bytes, stream);  // gstats + dcount + bucketCnt
    k_bcount<<<(E + 8191) / 8192, 1024, 0, stream>>>(edst, bucketCnt, E, nbuck);
    k_bscan2<<<1, 512, 0, stream>>>(bucketCnt, bbase, bcur, offs, nbuck, E, N);
    k_binA<<<(E + ACHUNK - 1) / ACHUNK, 256, 0, stream>>>(esrc, edst, ebuf, bcur, E, nbuck);
    k_binB<<<nbuck, 256, 0, stream>>>(ebuf, bbase, x, offs, dinv, m16A, csr, N);
    k_dhist<<<nb, 1024, 0, stream>>>(offs, dcount, batch, bnd, m16A, m16B, sinfo, N, G, ntiles);
    k_dscan<<<1, 256, 0, stream>>>(dcount, dcur);
    k_dscatter<<<nb, 1024, 0, stream>>>(offs, dinv, dcur, sinfo, N);

    // mirror rotation:
    //   L0: gather m16A -> agg; bn: agg -> m16B (scaled)          [res: none]
    //   L1: gather m16B -> agg; bn: agg + res(m16B) -> m16A (scaled)
    //   L2: gather m16A -> agg; bn: agg + res(m16A) -> m16B (unscaled, feeds pool)
    __half* gin[3]  = {m16A, m16B, m16A};
    __half* gout[3] = {m16B, m16A, m16B};

    const int gblocks = (ntiles + 3) / 4;  // one 16-node tile per wave, 4 waves/block

    for (int l = 0; l < 3; ++l) {
        float* gstat = gstats + (size_t)l * NSLICE * 128;
        k_gather_gemm<<<gblocks, 256, 0, stream>>>(sinfo, csr, (const __half*)gin[l],
                                                   convW + (size_t)l * DD * DD, convB + l * DD,
                                                   aggbuf, gstat, N, N);
        k_bn_ln_gelu<<<2048, 256, 0, stream>>>(aggbuf, gin[l], gstat, dinv,
                                               bn_g + l * DD, bn_b + l * DD,
                                               ln_g + l * DD, ln_b + l * DD,
                                               gout[l], N, l > 0 ? 1 : 0, l < 2 ? 1 : 0);
    }

    k_poolhead<<<G, 256, 0, stream>>>(m16B, bnd, W1, b1, ln1g, ln1b,
                                      W2, b2, ln2g, ln2b, W3, b3, out);
}